// Round 12
// baseline (453.301 us; speedup 1.0000x reference)
//
#include <hip/hip_runtime.h>

typedef unsigned short ushort_t;
typedef unsigned int uint_t;

typedef ushort_t ushortx8 __attribute__((ext_vector_type(8)));
typedef ushort_t ushortx4 __attribute__((ext_vector_type(4)));
typedef __bf16 bf16x8 __attribute__((ext_vector_type(8)));
typedef float f32x4 __attribute__((ext_vector_type(4)));

#define NCC 8192
#define NGG 4096
#define NPP 140
// LDS tile row stride (elements): multiple of 8 so ushortx8 (align 16) LDS ops
// are 16B-aligned; bank step 44 dwords == 12 mod 32 => 2-way aliasing (free).
#define LDS_STR 88

__device__ __forceinline__ float bf2f(ushort_t u) {
    uint_t i = ((uint_t)u) << 16;
    float f;
    __builtin_memcpy(&f, &i, 4);
    return f;
}
__device__ __forceinline__ ushort_t f2bf(float f) {
    uint_t i;
    __builtin_memcpy(&i, &f, 4);
    uint_t r = (i + 0x7FFFu + ((i >> 16) & 1u)) >> 16;
    return (ushort_t)r;
}
__device__ __forceinline__ float scrub(float x) {  // insurance: non-finite -> 0
    return __builtin_isfinite(x) ? x : 0.f;
}
__device__ __forceinline__ float selu_f(float x) {
    return x > 0.f ? 1.0507009873554805f * x : 1.7580993408473766f * expm1f(x);
}
__device__ __forceinline__ float wsum64(float x) {
    for (int o = 32; o; o >>= 1) x += __shfl_xor(x, o, 64);
    return x;
}

// ---------------- zero fill ----------------
__global__ __launch_bounds__(256) void sc_zero1(int* __restrict__ a, int na) {
    int i = blockIdx.x * 256 + threadIdx.x;
    if (i < na) a[i] = 0;
}

// ================= job structs =================
struct CntJob {
    const int* dst;
    const int* src;
    const float* w;
    uint_t* pw;      // packed (bf16(w)<<16)|src, edge order
    ushort_t* rank;  // rank within dst group
    int E;
    int* deg;
    int bstart;
};
struct CntBatch {
    CntJob j[6];
};
struct TrJob {
    const float* src;
    ushort_t* dst;
    int K, N, nx, nxy;
    int bstart;
};
struct TrBatch {
    TrJob j[6];
};
struct FillJob {
    const int* dst;
    const uint_t* pw;
    const ushort_t* rank;
    int E;
    const int* offs;
    uint_t* ep;
    int bstart;
};
struct FillBatch {
    FillJob j[6];
};
struct GemmJob {
    const void* A1;
    int lda1, K1, af1;
    const ushort_t* Bt1;
    const ushort_t* A2;
    int K2;
    const ushort_t* Bt2;
    const float* bias;
    ushort_t* C;
    int ldc, M;
    int mstart;  // prefix of 128-row m-blocks; unused jobs: mstart=INT_MAX
};
struct GemmBatch {
    GemmJob j[7];
};
struct GatherJob {
    const ushort_t* hsrc;
    int src_ld, src_n;
    const int* offs;
    const uint_t* ep;
    ushort_t* out;
    int row_start;
};
struct GatherBatch {
    GatherJob j[6];
};

// ================= prep: CSR count(+rank+pack) | weight transpose | emb gather =========
// Merged: independent; BW/atomic-bound count overlaps transpose + gather (m114).
struct PrepArgs {
    CntBatch cb;
    int bsC;
    TrBatch tb;
    int bsT;
    const float* emb;
    const int* pidx;
    ushort_t* hp;
    int nEmb;
};
__global__ __launch_bounds__(256) void sc_prep(PrepArgs pa) {
    __shared__ ushort_t t[32][33];
    int bx = blockIdx.x;
    if (bx < pa.bsC) {
        int r = 0;
#pragma unroll
        for (int i = 1; i < 6; ++i) r = (bx >= pa.cb.j[i].bstart) ? i : r;
        const CntJob& J = pa.cb.j[r];
        int e = (bx - J.bstart) * 256 + threadIdx.x;
        if (e < J.E) {
            int rk = atomicAdd(&J.deg[J.dst[e]], 1);
            J.rank[e] = (ushort_t)rk;
            J.pw[e] = ((uint_t)f2bf(J.w[e]) << 16) | (uint_t)J.src[e];
        }
        return;
    }
    bx -= pa.bsC;
    if (bx < pa.bsT) {
        int r = 0;
#pragma unroll
        for (int i = 1; i < 6; ++i) r = (bx >= pa.tb.j[i].bstart) ? i : r;
        const TrJob& J = pa.tb.j[r];
        int local = bx - J.bstart;
        int b = local / J.nxy, rem = local % J.nxy;
        int n0 = (rem % J.nx) * 32, k0 = (rem / J.nx) * 32;
        const float* s = J.src + (size_t)b * J.K * J.N;
        ushort_t* d = J.dst + (size_t)b * J.K * J.N;
        int x = threadIdx.x & 31, y = threadIdx.x >> 5;
        for (int i = y; i < 32; i += 8) {
            int k = k0 + i, n = n0 + x;
            t[i][x] = (k < J.K && n < J.N) ? f2bf(s[(size_t)k * J.N + n]) : (ushort_t)0;
        }
        __syncthreads();
        for (int i = y; i < 32; i += 8) {
            int n = n0 + i, k = k0 + x;
            if (n < J.N && k < J.K) d[(size_t)n * J.K + k] = t[x][i];
        }
        return;
    }
    bx -= pa.bsT;
    int i = bx * 256 + threadIdx.x;
    if (i < pa.nEmb) {
        int r = i >> 8, c = i & 255;
        int j = pa.pidx[r];
        j = (uint_t)j < (uint_t)NPP ? j : 0;
        pa.hp[i] = f2bf(pa.emb[(size_t)j * 256 + c]);
    }
}

// shfl-based scan: 3 barriers per 1024-chunk.
__global__ __launch_bounds__(1024) void sc_csr_scan6(const int* __restrict__ deg_base,
                                                     int* __restrict__ offs_base) {
    const int ndst[6] = {NCC, NGG, NPP, NGG, NGG, NPP};
    const int dstart[6] = {0, NCC, NCC + NGG, NCC + NGG + NPP, NCC + 2 * NGG + NPP,
                           NCC + 3 * NGG + NPP};
    const int ostart[6] = {0, NCC + 1, NCC + NGG + 2, NCC + NGG + NPP + 3,
                           NCC + 2 * NGG + NPP + 4, NCC + 3 * NGG + NPP + 5};
    int r = blockIdx.x;
    const int* deg = deg_base + dstart[r];
    int* offs = offs_base + ostart[r];
    int n = ndst[r];
    __shared__ int wsum[16];
    __shared__ int carry;
    int tid = threadIdx.x, wave = tid >> 6, lane = tid & 63;
    if (tid == 0) carry = 0;
    __syncthreads();
    for (int base = 0; base < n; base += 1024) {
        int i = base + tid;
        int v = (i < n) ? deg[i] : 0;
        int x = v;
#pragma unroll
        for (int o = 1; o < 64; o <<= 1) {
            int tv = __shfl_up(x, o, 64);
            if (lane >= o) x += tv;
        }
        if (lane == 63) wsum[wave] = x;
        __syncthreads();
        if (tid == 0) {
            int acc = 0;
#pragma unroll
            for (int k = 0; k < 16; ++k) {
                int tv = wsum[k];
                wsum[k] = acc;
                acc += tv;
            }
        }
        __syncthreads();
        int incl = x + wsum[wave];
        int cr = carry;
        if (i < n) offs[i] = cr + incl - v;
        __syncthreads();
        if (tid == 1023) carry = cr + incl;
        __syncthreads();
    }
    if (tid == 0) offs[n] = carry;
}

// ================= GEMM body (128x64 tile) ==========
__device__ __forceinline__ void gemm_body(const GemmBatch& gbat, int mbx, int n0, ushort_t* As,
                                          ushort_t* Bs) {
    int r = 0;
#pragma unroll
    for (int i = 1; i < 7; ++i) r = (mbx >= gbat.j[i].mstart) ? i : r;
    const void* JA1 = gbat.j[r].A1;
    const int lda1 = gbat.j[r].lda1, K1j = gbat.j[r].K1, af1 = gbat.j[r].af1;
    const ushort_t* JBt1 = gbat.j[r].Bt1;
    const ushort_t* JA2 = gbat.j[r].A2;
    const int K2j = gbat.j[r].K2;
    const ushort_t* JBt2 = gbat.j[r].Bt2;
    const float* bias = gbat.j[r].bias;
    ushort_t* C = gbat.j[r].C;
    const int ldc = gbat.j[r].ldc, M = gbat.j[r].M;
    const int tid = threadIdx.x;
    const int wave = tid >> 6, lane = tid & 63;
    const int lr = lane & 15, lq = lane >> 4;
    const int m0 = (mbx - gbat.j[r].mstart) * 128;
    f32x4 acc[2][4] = {};
    for (int pass = 0; pass < 2; ++pass) {
        const void* A = pass ? (const void*)JA2 : JA1;
        const ushort_t* Bt = pass ? JBt2 : JBt1;
        const int K = pass ? K2j : K1j;
        const int lda = pass ? 256 : lda1;
        const int af = pass ? 0 : af1;
        if (K == 0 || A == nullptr) continue;
        for (int k0 = 0; k0 < K; k0 += 64) {
            __syncthreads();
#pragma unroll
            for (int i = 0; i < 4; ++i) {
                int g = tid + i * 256;
                int rr = g >> 3, c = (g & 7) * 8;
                ushortx8 v = {0, 0, 0, 0, 0, 0, 0, 0};
                int gm = m0 + rr;
                if (gm < M) {
                    if (af) {
                        const float* Af = (const float*)A;
                        float4 f0 = *(const float4*)(Af + (size_t)gm * lda + k0 + c);
                        float4 f1 = *(const float4*)(Af + (size_t)gm * lda + k0 + c + 4);
                        v[0] = f2bf(f0.x);
                        v[1] = f2bf(f0.y);
                        v[2] = f2bf(f0.z);
                        v[3] = f2bf(f0.w);
                        v[4] = f2bf(f1.x);
                        v[5] = f2bf(f1.y);
                        v[6] = f2bf(f1.z);
                        v[7] = f2bf(f1.w);
                    } else {
                        v = *(const ushortx8*)((const ushort_t*)A + (size_t)gm * lda + k0 + c);
                    }
                }
                *(ushortx8*)(&As[rr * LDS_STR + c]) = v;
            }
#pragma unroll
            for (int i = 0; i < 2; ++i) {
                int g = tid + i * 256;
                int rr = g >> 3, c = (g & 7) * 8;
                int gn = n0 + rr;
                ushortx8 v = *(const ushortx8*)(Bt + (size_t)gn * K + k0 + c);
                *(ushortx8*)(&Bs[rr * LDS_STR + c]) = v;
            }
            __syncthreads();
#pragma unroll
            for (int kk = 0; kk < 64; kk += 32) {
                bf16x8 a0 = __builtin_bit_cast(
                    bf16x8, *(const ushortx8*)(&As[(wave * 32 + lr) * LDS_STR + kk + lq * 8]));
                bf16x8 a1 = __builtin_bit_cast(
                    bf16x8,
                    *(const ushortx8*)(&As[(wave * 32 + 16 + lr) * LDS_STR + kk + lq * 8]));
                bf16x8 b0 = __builtin_bit_cast(
                    bf16x8, *(const ushortx8*)(&Bs[(lr)*LDS_STR + kk + lq * 8]));
                bf16x8 b1 = __builtin_bit_cast(
                    bf16x8, *(const ushortx8*)(&Bs[(16 + lr) * LDS_STR + kk + lq * 8]));
                bf16x8 b2 = __builtin_bit_cast(
                    bf16x8, *(const ushortx8*)(&Bs[(32 + lr) * LDS_STR + kk + lq * 8]));
                bf16x8 b3 = __builtin_bit_cast(
                    bf16x8, *(const ushortx8*)(&Bs[(48 + lr) * LDS_STR + kk + lq * 8]));
                acc[0][0] = __builtin_amdgcn_mfma_f32_16x16x32_bf16(a0, b0, acc[0][0], 0, 0, 0);
                acc[0][1] = __builtin_amdgcn_mfma_f32_16x16x32_bf16(a0, b1, acc[0][1], 0, 0, 0);
                acc[0][2] = __builtin_amdgcn_mfma_f32_16x16x32_bf16(a0, b2, acc[0][2], 0, 0, 0);
                acc[0][3] = __builtin_amdgcn_mfma_f32_16x16x32_bf16(a0, b3, acc[0][3], 0, 0, 0);
                acc[1][0] = __builtin_amdgcn_mfma_f32_16x16x32_bf16(a1, b0, acc[1][0], 0, 0, 0);
                acc[1][1] = __builtin_amdgcn_mfma_f32_16x16x32_bf16(a1, b1, acc[1][1], 0, 0, 0);
                acc[1][2] = __builtin_amdgcn_mfma_f32_16x16x32_bf16(a1, b2, acc[1][2], 0, 0, 0);
                acc[1][3] = __builtin_amdgcn_mfma_f32_16x16x32_bf16(a1, b3, acc[1][3], 0, 0, 0);
            }
        }
    }
#pragma unroll
    for (int mt = 0; mt < 2; ++mt)
#pragma unroll
        for (int nt = 0; nt < 4; ++nt) {
            int col = n0 + nt * 16 + lr;
            float bb = bias[col];
#pragma unroll
            for (int v = 0; v < 4; ++v) {
                int row = m0 + wave * 32 + mt * 16 + lq * 4 + v;
                if (row >= M) continue;
                C[(size_t)row * ldc + col] = f2bf(scrub(acc[mt][nt][v] + bb));
            }
        }
}

// ================= gather body (wave per row, unroll-16 ILP) ==========
__device__ __forceinline__ void gather_body(const GatherBatch& gb, int bx, int total_rows) {
    int grow = bx * 4 + ((int)threadIdx.x >> 6);
    if (grow >= total_rows) return;
    int r = 0;
#pragma unroll
    for (int i = 1; i < 6; ++i) r = (grow >= gb.j[i].row_start) ? i : r;
    r = __builtin_amdgcn_readfirstlane(r);  // wave-uniform: scalar descriptor loads
    const ushort_t* hsrc = gb.j[r].hsrc;
    const int src_ld = gb.j[r].src_ld, src_n = gb.j[r].src_n;
    const int* offs = gb.j[r].offs;
    const uint_t* ep = gb.j[r].ep;
    ushort_t* out = gb.j[r].out;
    int row = grow - gb.j[r].row_start;
    int lane = threadIdx.x & 63, c = lane * 4;
    int s0 = offs[row], s1 = offs[row + 1];
    float a0 = 0.f, a1 = 0.f, a2 = 0.f, a3 = 0.f;
    for (int base = s0; base < s1; base += 64) {
        int e = base + lane;
        uint_t myp = (e < s1) ? ep[e] : 0u;  // pad lanes: src=0, w=bf16(0)=+0
        int cnt = s1 - base;
        cnt = cnt < 64 ? cnt : 64;
        int cnt16 = (cnt + 15) & ~15;  // padded groups add w=0 terms
        for (int jj = 0; jj < cnt16; jj += 16) {
#pragma unroll
            for (int u = 0; u < 16; ++u) {  // 16 independent gather loads in flight
                uint_t pw = (uint_t)__shfl((int)myp, jj + u, 64);
                int s = (int)(pw & 0xFFFFu);
                s = (uint_t)s < (uint_t)src_n ? s : 0;  // clamp: defects->wrong, not wild
                float w = bf2f((ushort_t)(pw >> 16));
                ushortx4 v = *(const ushortx4*)(hsrc + (size_t)s * src_ld + c);
                a0 += w * bf2f(v[0]);
                a1 += w * bf2f(v[1]);
                a2 += w * bf2f(v[2]);
                a3 += w * bf2f(v[3]);
            }
        }
    }
    float inv = 1.f / fmaxf((float)(s1 - s0), 1.f);
    ushort_t* o = out + (size_t)row * 256 + c;
    o[0] = f2bf(scrub(a0 * inv));
    o[1] = f2bf(scrub(a1 * inv));
    o[2] = f2bf(scrub(a2 * inv));
    o[3] = f2bf(scrub(a3 * inv));
}

// ---------------- batched GEMMs (2D grid: relation GEMMs) ----------------
__global__ __launch_bounds__(256) void sc_gemm_batch(GemmBatch gbat) {
    __shared__ __align__(16) ushort_t As[128 * LDS_STR];
    __shared__ __align__(16) ushort_t Bs[64 * LDS_STR];
    gemm_body(gbat, blockIdx.x, blockIdx.y * 64, As, Bs);
}

// ---------------- merged: CSR fill (BW-bound) + emb GEMMs (MFMA-bound) ----------------
struct FillGemmArgs {
    GemmBatch gb;
    int gemmBlocks;  // ms*4 flattened (mb = bx>>2, ntile = bx&3)
    FillBatch fb;
};
__global__ __launch_bounds__(256) void sc_fill_gemm(FillGemmArgs fg) {
    __shared__ __align__(16) ushort_t As[128 * LDS_STR];
    __shared__ __align__(16) ushort_t Bs[64 * LDS_STR];
    int bx = blockIdx.x;
    if (bx >= fg.gemmBlocks) {
        bx -= fg.gemmBlocks;
        int r = 0;
#pragma unroll
        for (int i = 1; i < 6; ++i) r = (bx >= fg.fb.j[i].bstart) ? i : r;
        const FillJob& J = fg.fb.j[r];
        int e = (bx - J.bstart) * 256 + threadIdx.x;
        if (e < J.E) {
            int d = J.dst[e];
            J.ep[J.offs[d] + (int)J.rank[e]] = J.pw[e];
        }
        return;
    }
    gemm_body(fg.gb, bx >> 2, (bx & 3) * 64, As, Bs);
}

// ---------------- merged: 6 gathers (latency-bound) + mlp GEMM (MFMA-bound) ----------
// Round-12: mlp only depends on hc_l (not the gathers) -> overlap (m114).
struct GatherMlpArgs {
    GatherBatch gb;
    int gatherBlocks, totalRows;
    GemmBatch mb;  // single mlp job
};
__global__ __launch_bounds__(256) void sc_gather_mlp(GatherMlpArgs ga) {
    __shared__ __align__(16) ushort_t As[128 * LDS_STR];
    __shared__ __align__(16) ushort_t Bs[64 * LDS_STR];
    int bx = blockIdx.x;
    if (bx < ga.gatherBlocks) {
        gather_body(ga.gb, bx, ga.totalRows);
        return;
    }
    bx -= ga.gatherBlocks;
    gemm_body(ga.mb, bx >> 2, (bx & 3) * 64, As, Bs);
}

// ---------------- standalone MFMA bf16 GEMM (final proj, f32 out) ----------------
__global__ __launch_bounds__(256) void sc_gemm(const ushort_t* __restrict__ A1, int lda1,
                                               const ushort_t* __restrict__ Bt1, int K1,
                                               const float* __restrict__ bias,
                                               float* __restrict__ Cf, int ldc, int M, int N) {
    __shared__ __align__(16) ushort_t As[128 * LDS_STR];
    __shared__ __align__(16) ushort_t Bs[64 * LDS_STR];
    const int tid = threadIdx.x;
    const int wave = tid >> 6, lane = tid & 63;
    const int lr = lane & 15, lq = lane >> 4;
    const int m0 = blockIdx.x * 128, n0 = blockIdx.y * 64;
    f32x4 acc[2][4] = {};
    for (int k0 = 0; k0 < K1; k0 += 64) {
        __syncthreads();
#pragma unroll
        for (int i = 0; i < 4; ++i) {
            int g = tid + i * 256;
            int r = g >> 3, c = (g & 7) * 8;
            ushortx8 v = {0, 0, 0, 0, 0, 0, 0, 0};
            int gm = m0 + r;
            if (gm < M) v = *(const ushortx8*)(A1 + (size_t)gm * lda1 + k0 + c);
            *(ushortx8*)(&As[r * LDS_STR + c]) = v;
        }
#pragma unroll
        for (int i = 0; i < 2; ++i) {
            int g = tid + i * 256;
            int r = g >> 3, c = (g & 7) * 8;
            ushortx8 v = {0, 0, 0, 0, 0, 0, 0, 0};
            int gn = n0 + r;
            if (gn < N) v = *(const ushortx8*)(Bt1 + (size_t)gn * K1 + k0 + c);
            *(ushortx8*)(&Bs[r * LDS_STR + c]) = v;
        }
        __syncthreads();
#pragma unroll
        for (int kk = 0; kk < 64; kk += 32) {
            bf16x8 a0 = __builtin_bit_cast(
                bf16x8, *(const ushortx8*)(&As[(wave * 32 + lr) * LDS_STR + kk + lq * 8]));
            bf16x8 a1 = __builtin_bit_cast(
                bf16x8, *(const ushortx8*)(&As[(wave * 32 + 16 + lr) * LDS_STR + kk + lq * 8]));
            bf16x8 b0 =
                __builtin_bit_cast(bf16x8, *(const ushortx8*)(&Bs[(lr)*LDS_STR + kk + lq * 8]));
            bf16x8 b1 = __builtin_bit_cast(
                bf16x8, *(const ushortx8*)(&Bs[(16 + lr) * LDS_STR + kk + lq * 8]));
            bf16x8 b2 = __builtin_bit_cast(
                bf16x8, *(const ushortx8*)(&Bs[(32 + lr) * LDS_STR + kk + lq * 8]));
            bf16x8 b3 = __builtin_bit_cast(
                bf16x8, *(const ushortx8*)(&Bs[(48 + lr) * LDS_STR + kk + lq * 8]));
            acc[0][0] = __builtin_amdgcn_mfma_f32_16x16x32_bf16(a0, b0, acc[0][0], 0, 0, 0);
            acc[0][1] = __builtin_amdgcn_mfma_f32_16x16x32_bf16(a0, b1, acc[0][1], 0, 0, 0);
            acc[0][2] = __builtin_amdgcn_mfma_f32_16x16x32_bf16(a0, b2, acc[0][2], 0, 0, 0);
            acc[0][3] = __builtin_amdgcn_mfma_f32_16x16x32_bf16(a0, b3, acc[0][3], 0, 0, 0);
            acc[1][0] = __builtin_amdgcn_mfma_f32_16x16x32_bf16(a1, b0, acc[1][0], 0, 0, 0);
            acc[1][1] = __builtin_amdgcn_mfma_f32_16x16x32_bf16(a1, b1, acc[1][1], 0, 0, 0);
            acc[1][2] = __builtin_amdgcn_mfma_f32_16x16x32_bf16(a1, b2, acc[1][2], 0, 0, 0);
            acc[1][3] = __builtin_amdgcn_mfma_f32_16x16x32_bf16(a1, b3, acc[1][3], 0, 0, 0);
        }
    }
#pragma unroll
    for (int mt = 0; mt < 2; ++mt)
#pragma unroll
        for (int nt = 0; nt < 4; ++nt) {
            int col = n0 + nt * 16 + lr;
            if (col >= N) continue;
            float bb = bias ? bias[col] : 0.f;
#pragma unroll
            for (int v = 0; v < 4; ++v) {
                int row = m0 + wave * 32 + mt * 16 + lq * 4 + v;
                if (row >= M) continue;
                Cf[(size_t)row * ldc + col] = scrub(acc[mt][nt][v] + bb);
            }
        }
}

// ---------------- fused selu+LN chains, 3 node types in one dispatch ----------------
struct LnJob {
    const ushort_t *sA, *sB, *sC;
    const float *g1, *b1, *g2, *b2;
    ushort_t* out;
    int out_ld;
    int row_start;
};
struct LnBatch {
    LnJob j[3];
};
__global__ __launch_bounds__(256) void sc_fuse_ln_all(LnBatch lb, int total_rows) {
    int grow = blockIdx.x * 4 + (threadIdx.x >> 6);
    if (grow >= total_rows) return;
    int r = 0;
#pragma unroll
    for (int i = 1; i < 3; ++i) r = (grow >= lb.j[i].row_start) ? i : r;
    r = __builtin_amdgcn_readfirstlane(r);
    const ushort_t* srcs[3] = {lb.j[r].sA, lb.j[r].sB, lb.j[r].sC};
    const float* g1 = lb.j[r].g1;
    const float* b1 = lb.j[r].b1;
    const float* g2 = lb.j[r].g2;
    const float* b2 = lb.j[r].b2;
    ushort_t* out = lb.j[r].out;
    int out_ld = lb.j[r].out_ld;
    int row = grow - lb.j[r].row_start;
    int lane = threadIdx.x & 63, c = lane * 4;
    float t[4] = {0.f, 0.f, 0.f, 0.f};
#pragma unroll
    for (int si = 0; si < 3; ++si) {
        const ushort_t* s = srcs[si];
        if (!s) continue;
        ushortx4 v = *(const ushortx4*)(s + (size_t)row * 256 + c);
        float x0 = selu_f(scrub(bf2f(v[0]))), x1 = selu_f(scrub(bf2f(v[1])));
        float x2 = selu_f(scrub(bf2f(v[2]))), x3 = selu_f(scrub(bf2f(v[3])));
        float mu = wsum64(x0 + x1 + x2 + x3) * (1.f / 256.f);
        float d0 = x0 - mu, d1 = x1 - mu, d2 = x2 - mu, d3 = x3 - mu;
        float var = wsum64(d0 * d0 + d1 * d1 + d2 * d2 + d3 * d3) * (1.f / 256.f);
        float rr = rsqrtf(var + 1e-5f);
        t[0] += d0 * rr * g1[c + 0] + b1[c + 0];
        t[1] += d1 * rr * g1[c + 1] + b1[c + 1];
        t[2] += d2 * rr * g1[c + 2] + b1[c + 2];
        t[3] += d3 * rr * g1[c + 3] + b1[c + 3];
    }
    float x0 = selu_f(scrub(t[0])), x1 = selu_f(scrub(t[1]));
    float x2 = selu_f(scrub(t[2])), x3 = selu_f(scrub(t[3]));
    float mu = wsum64(x0 + x1 + x2 + x3) * (1.f / 256.f);
    float d0 = x0 - mu, d1 = x1 - mu, d2 = x2 - mu, d3 = x3 - mu;
    float var = wsum64(d0 * d0 + d1 * d1 + d2 * d2 + d3 * d3) * (1.f / 256.f);
    float rr = rsqrtf(var + 1e-5f);
    ushort_t* o = out + (size_t)row * out_ld + c;
    o[0] = f2bf(scrub(d0 * rr * g2[c + 0] + b2[c + 0]));
    o[1] = f2bf(scrub(d1 * rr * g2[c + 1] + b2[c + 1]));
    o[2] = f2bf(scrub(d2 * rr * g2[c + 2] + b2[c + 2]));
    o[3] = f2bf(scrub(d3 * rr * g2[c + 3] + b2[c + 3]));
}

static inline int cdivi(int a, int b) { return (a + b - 1) / b; }

extern "C" void kernel_launch(void* const* d_in, const int* in_sizes, int n_in, void* d_out,
                              int out_size, void* d_ws, size_t ws_size, hipStream_t stream) {
    const float* cell_feat = (const float*)d_in[0];
    const float* gene_feat = (const float*)d_in[1];
    const int* pro_idx = (const int*)d_in[2];
    const int* edge_src[6] = {(const int*)d_in[3],  (const int*)d_in[6],  (const int*)d_in[9],
                              (const int*)d_in[12], (const int*)d_in[15], (const int*)d_in[18]};
    const int* edge_dst[6] = {(const int*)d_in[4],  (const int*)d_in[7],  (const int*)d_in[10],
                              (const int*)d_in[13], (const int*)d_in[16], (const int*)d_in[19]};
    const float* edge_w[6] = {(const float*)d_in[5],  (const float*)d_in[8],
                              (const float*)d_in[11], (const float*)d_in[14],
                              (const float*)d_in[17], (const float*)d_in[20]};
    const float* W_emb_cell = (const float*)d_in[21];
    const float* b_emb_cell = (const float*)d_in[22];
    const float* W_emb_gene = (const float*)d_in[23];
    const float* b_emb_gene = (const float*)d_in[24];
    const float* emb_pro = (const float*)d_in[25];
    const float* W_mlpcell = (const float*)d_in[26];
    const float* b_mlpcell = (const float*)d_in[27];
    const float* W_sage_self = (const float*)d_in[28];
    const float* W_sage_neigh = (const float*)d_in[29];
    const float* b_sage = (const float*)d_in[30];
    const float* ln1_g = (const float*)d_in[31];
    const float* ln1_b = (const float*)d_in[32];
    const float* ln2_g = (const float*)d_in[33];
    const float* ln2_b = (const float*)d_in[34];
    const float* W_last = (const float*)d_in[35];
    const float* b_last = (const float*)d_in[36];

    const int E_obs = in_sizes[3], E_sym = in_sizes[9], E_coexp = in_sizes[15],
              E_ppi = in_sizes[18];
    const int Er[6] = {E_obs, E_obs, E_sym, E_sym, E_coexp, E_ppi};
    const int Nd[6] = {NCC, NGG, NPP, NGG, NGG, NPP};

    // ---- workspace carve ----
    char* p = (char*)d_ws;
    auto carve = [&](size_t bytes) -> char* {
        char* r = p;
        p += ((bytes + 255) & ~(size_t)255);
        return r;
    };
    ushort_t* hist = (ushort_t*)carve((size_t)NCC * 768 * 2);
    ushort_t* hg = (ushort_t*)carve((size_t)NGG * 256 * 2);
    ushort_t* hp = (ushort_t*)carve((size_t)NPP * 256 * 2);
    ushort_t* n_obs = (ushort_t*)carve((size_t)NCC * 256 * 2);
    ushort_t* n_robs = (ushort_t*)carve((size_t)NGG * 256 * 2);
    ushort_t* n_sym = (ushort_t*)carve((size_t)NPP * 256 * 2);
    ushort_t* n_rsym = (ushort_t*)carve((size_t)NGG * 256 * 2);
    ushort_t* n_coexp = (ushort_t*)carve((size_t)NGG * 256 * 2);
    ushort_t* n_ppi = (ushort_t*)carve((size_t)NPP * 256 * 2);
    ushort_t* s_obs = (ushort_t*)carve((size_t)NCC * 256 * 2);
    ushort_t* s_robs = (ushort_t*)carve((size_t)NGG * 256 * 2);
    ushort_t* s_sym = (ushort_t*)carve((size_t)NPP * 256 * 2);
    ushort_t* s_rsym = (ushort_t*)carve((size_t)NGG * 256 * 2);
    ushort_t* s_coexp = (ushort_t*)carve((size_t)NGG * 256 * 2);
    ushort_t* s_ppi = (ushort_t*)carve((size_t)NPP * 256 * 2);
    ushort_t* s_mlp = (ushort_t*)carve((size_t)NCC * 256 * 2);
    ushort_t* Wt_emb_cell = (ushort_t*)carve((size_t)512 * 256 * 2);
    ushort_t* Wt_emb_gene = (ushort_t*)carve((size_t)512 * 256 * 2);
    ushort_t* Wt_mlp = (ushort_t*)carve((size_t)2 * 256 * 256 * 2);
    ushort_t* Wt_self = (ushort_t*)carve((size_t)12 * 256 * 256 * 2);
    ushort_t* Wt_neigh = (ushort_t*)carve((size_t)12 * 256 * 256 * 2);
    ushort_t* Wt_last = (ushort_t*)carve((size_t)140 * 768 * 2);
    const int NDTOT = NCC + 3 * NGG + 2 * NPP;  // 20760
    int* deg_all = (int*)carve((size_t)NDTOT * 4);
    int* offs_all = (int*)carve((size_t)(NDTOT + 6) * 4);
    const int ETOT = 2 * E_obs + 2 * E_sym + E_coexp + E_ppi;
    uint_t* pw_all = (uint_t*)carve((size_t)ETOT * 4);        // packed, edge order
    ushort_t* rank_all = (ushort_t*)carve((size_t)ETOT * 2);  // rank within dst group
    uint_t* ep_all = (uint_t*)carve((size_t)ETOT * 4);        // packed, CSR order
    (void)ws_size;
    (void)n_in;
    (void)out_size;

    const int dS[6] = {0, NCC, NCC + NGG, NCC + NGG + NPP, NCC + 2 * NGG + NPP,
                       NCC + 3 * NGG + NPP};
    const int oS[6] = {0, NCC + 1, NCC + NGG + 2, NCC + NGG + NPP + 3, NCC + 2 * NGG + NPP + 4,
                       NCC + 3 * NGG + NPP + 5};
    int eS[6];
    eS[0] = 0;
    eS[1] = eS[0] + E_obs;
    eS[2] = eS[1] + E_obs;
    eS[3] = eS[2] + E_sym;
    eS[4] = eS[3] + E_sym;
    eS[5] = eS[4] + E_coexp;

    // ---- zero deg, then merged prep (count+rank+pack | transposes | emb gather) ----
    sc_zero1<<<cdivi(NDTOT, 256), 256, 0, stream>>>(deg_all, NDTOT);
    {
        PrepArgs pa;
        int bs = 0;
        for (int r = 0; r < 6; ++r) {
            pa.cb.j[r] = {edge_dst[r], edge_src[r], edge_w[r], pw_all + eS[r], rank_all + eS[r],
                          Er[r], deg_all + dS[r], bs};
            bs += cdivi(Er[r], 256);
        }
        pa.bsC = bs;
        int bt = 0;
        auto add = [&](int idx, const float* s, ushort_t* d, int B, int K, int N) {
            int nx = cdivi(N, 32), ny = cdivi(K, 32);
            pa.tb.j[idx] = {s, d, K, N, nx, nx * ny, bt};
            bt += B * nx * ny;
        };
        add(0, W_emb_cell, Wt_emb_cell, 1, 512, 256);
        add(1, W_emb_gene, Wt_emb_gene, 1, 512, 256);
        add(2, W_mlpcell, Wt_mlp, 2, 256, 256);
        add(3, W_sage_self, Wt_self, 12, 256, 256);
        add(4, W_sage_neigh, Wt_neigh, 12, 256, 256);
        add(5, W_last, Wt_last, 1, 768, 140);
        pa.bsT = bt;
        pa.emb = emb_pro;
        pa.pidx = pro_idx;
        pa.hp = hp;
        pa.nEmb = NPP * 256;
        int bsE = cdivi(NPP * 256, 256);
        sc_prep<<<pa.bsC + pa.bsT + bsE, 256, 0, stream>>>(pa);
    }
    sc_csr_scan6<<<6, 1024, 0, stream>>>(deg_all, offs_all);
    // ---- merged: CSR fill + both emb GEMMs (independent; BW + MFMA overlap) ----
    {
        FillGemmArgs fg;
        for (int i = 0; i < 7; ++i) fg.gb.j[i].mstart = 0x7FFFFFFF;
        fg.gb.j[0] = {cell_feat, 512, 512, 1, Wt_emb_cell, nullptr, 0, nullptr, b_emb_cell, hist,
                      768, NCC, 0};
        fg.gb.j[1] = {gene_feat, 512, 512, 1, Wt_emb_gene, nullptr, 0, nullptr, b_emb_gene, hg,
                      256, NGG, 64};
        fg.gemmBlocks = 96 * 4;
        int bs = 0;
        for (int r = 0; r < 6; ++r) {
            fg.fb.j[r] = {edge_dst[r], pw_all + eS[r], rank_all + eS[r], Er[r], offs_all + oS[r],
                          ep_all + eS[r], bs};
            bs += cdivi(Er[r], 256);
        }
        sc_fill_gemm<<<fg.gemmBlocks + bs, 256, 0, stream>>>(fg);
    }

    // ---- layers ----
    for (int l = 0; l < 2; ++l) {
        const ushort_t* hc_l = hist + l * 256;  // row stride 768
        const size_t WSZ = 65536;
        // 6 neighbor-mean gathers + mlp GEMM in one dispatch (independent)
        {
            GatherMlpArgs ga;
            const ushort_t* hs[6] = {hg, hc_l, hg, hp, hg, hp};
            const int lds[6] = {256, 768, 256, 256, 256, 256};
            const int sn[6] = {NGG, NCC, NGG, NPP, NGG, NPP};
            ushort_t* outs[6] = {n_obs, n_robs, n_sym, n_rsym, n_coexp, n_ppi};
            int rs = 0;
            for (int r = 0; r < 6; ++r) {
                ga.gb.j[r] = {hs[r], lds[r], sn[r], offs_all + oS[r], ep_all + eS[r], outs[r],
                              rs};
                rs += Nd[r];
            }
            ga.totalRows = rs;
            ga.gatherBlocks = cdivi(rs, 4);
            for (int i = 0; i < 7; ++i) ga.mb.j[i].mstart = 0x7FFFFFFF;
            ga.mb.j[0] = {hc_l, 768, 256, 0, Wt_mlp + (size_t)l * WSZ, nullptr, 0, nullptr,
                          b_mlpcell + l * 256, s_mlp, 256, NCC, 0};
            ga.mb.j[1].mstart = 0x7FFFFFFF;
            sc_gather_mlp<<<ga.gatherBlocks + 64 * 4, 256, 0, stream>>>(ga);
        }
        // 6 relation GEMMs in one dispatch
        {
            GemmBatch gbat;
            for (int i = 0; i < 7; ++i) gbat.j[i].mstart = 0x7FFFFFFF;
            const ushort_t* dstf[6] = {hc_l, hg, hp, hg, hg, hp};
            const int dld[6] = {768, 256, 256, 256, 256, 256};
            const ushort_t* nb[6] = {n_obs, n_robs, n_sym, n_rsym, n_coexp, n_ppi};
            ushort_t* so[6] = {s_obs, s_robs, s_sym, s_rsym, s_coexp, s_ppi};
            int ms = 0;
            for (int r = 0; r < 6; ++r) {
                gbat.j[r] = {dstf[r],
                             dld[r],
                             256,
                             0,
                             Wt_self + (size_t)(l * 6 + r) * WSZ,
                             nb[r],
                             256,
                             Wt_neigh + (size_t)(l * 6 + r) * WSZ,
                             b_sage + (l * 6 + r) * 256,
                             so[r],
                             256,
                             Nd[r],
                             ms};
                ms += cdivi(Nd[r], 128);
            }
            sc_gemm_batch<<<dim3(ms, 4), 256, 0, stream>>>(gbat);
        }
        // 3 fused selu+LN chains in one dispatch
        {
            LnBatch lb;
            lb.j[0] = {s_robs, s_rsym, s_coexp, ln1_g + (l * 3 + 0) * 256,
                       ln1_b + (l * 3 + 0) * 256, ln2_g + (l * 3 + 0) * 256,
                       ln2_b + (l * 3 + 0) * 256, hg, 256, 0};
            lb.j[1] = {s_sym, s_ppi, nullptr, ln1_g + (l * 3 + 1) * 256,
                       ln1_b + (l * 3 + 1) * 256, ln2_g + (l * 3 + 1) * 256,
                       ln2_b + (l * 3 + 1) * 256, hp, 256, NGG};
            lb.j[2] = {s_obs, s_mlp, nullptr, ln1_g + (l * 3 + 2) * 256,
                       ln1_b + (l * 3 + 2) * 256, ln2_g + (l * 3 + 2) * 256,
                       ln2_b + (l * 3 + 2) * 256, hist + (l + 1) * 256, 768, NGG + NPP};
            int rs = NGG + NPP + NCC;
            sc_fuse_ln_all<<<cdivi(rs, 4), 256, 0, stream>>>(lb, rs);
        }
    }

    // ---- final projection: out(f32) = hist[8192,768] @ W_last + b_last ----
    sc_gemm<<<dim3(64, 3), 256, 0, stream>>>(hist, 768, Wt_last, 768, b_last, (float*)d_out, 140,
                                             NCC, 140);
}

// Round 13
// 426.905 us; speedup vs baseline: 1.0618x; 1.0618x over previous
//
#include <hip/hip_runtime.h>

typedef unsigned short ushort_t;
typedef unsigned int uint_t;

typedef ushort_t ushortx8 __attribute__((ext_vector_type(8)));
typedef ushort_t ushortx4 __attribute__((ext_vector_type(4)));
typedef __bf16 bf16x8 __attribute__((ext_vector_type(8)));
typedef float f32x4 __attribute__((ext_vector_type(4)));

#define NCC 8192
#define NGG 4096
#define NPP 140
// LDS tile row stride (elements): multiple of 8 so ushortx8 (align 16) LDS ops
// are 16B-aligned; bank step 44 dwords == 12 mod 32 => 2-way aliasing (free).
#define LDS_STR 88

__device__ __forceinline__ float bf2f(ushort_t u) {
    uint_t i = ((uint_t)u) << 16;
    float f;
    __builtin_memcpy(&f, &i, 4);
    return f;
}
__device__ __forceinline__ ushort_t f2bf(float f) {
    uint_t i;
    __builtin_memcpy(&i, &f, 4);
    uint_t r = (i + 0x7FFFu + ((i >> 16) & 1u)) >> 16;
    return (ushort_t)r;
}
__device__ __forceinline__ float scrub(float x) {  // insurance: non-finite -> 0
    return __builtin_isfinite(x) ? x : 0.f;
}
__device__ __forceinline__ float selu_f(float x) {
    return x > 0.f ? 1.0507009873554805f * x : 1.7580993408473766f * expm1f(x);
}
__device__ __forceinline__ float wsum64(float x) {
    for (int o = 32; o; o >>= 1) x += __shfl_xor(x, o, 64);
    return x;
}

// ---------------- zero fill ----------------
__global__ __launch_bounds__(256) void sc_zero1(int* __restrict__ a, int na) {
    int i = blockIdx.x * 256 + threadIdx.x;
    if (i < na) a[i] = 0;
}

// ================= job structs =================
struct CntJob {
    const int* dst;
    const int* src;
    const float* w;
    uint_t* pw;      // packed (bf16(w)<<16)|src, edge order
    ushort_t* rank;  // rank within dst group
    int E;
    int* deg;
    int bstart;
};
struct CntBatch {
    CntJob j[6];
};
struct TrJob {
    const float* src;
    ushort_t* dst;
    int K, N, nx, nxy;
    int bstart;
};
struct TrBatch {
    TrJob j[6];
};
struct FillJob {
    const int* dst;
    const uint_t* pw;
    const ushort_t* rank;
    int E;
    const int* offs;
    uint_t* ep;
    int bstart;
};
struct FillBatch {
    FillJob j[6];
};
struct GemmJob {
    const void* A1;
    int lda1, K1, af1;
    const ushort_t* Bt1;
    const ushort_t* A2;
    int K2;
    const ushort_t* Bt2;
    const float* bias;
    ushort_t* C;
    int ldc, M;
    int mstart;  // prefix of 128-row m-blocks; unused jobs: mstart=INT_MAX
};
struct GemmBatch {
    GemmJob j[7];
};

// ================= prep: CSR count(+rank+pack) | weight transpose | emb gather =========
// Merged: independent; BW/atomic-bound count overlaps transpose + gather (m114).
// NOTE (r12 lesson): do NOT merge the gather or other latency-bound kernels with
// LDS-heavy GEMM roles — merged kernels pay max(LDS,VGPR) across roles and the
// occupancy loss kills latency-bound code (r12: 33KB LDS -> 23% occ -> +25us).
struct PrepArgs {
    CntBatch cb;
    int bsC;
    TrBatch tb;
    int bsT;
    const float* emb;
    const int* pidx;
    ushort_t* hp;
    int nEmb;
};
__global__ __launch_bounds__(256) void sc_prep(PrepArgs pa) {
    __shared__ ushort_t t[32][33];
    int bx = blockIdx.x;
    if (bx < pa.bsC) {
        int r = 0;
#pragma unroll
        for (int i = 1; i < 6; ++i) r = (bx >= pa.cb.j[i].bstart) ? i : r;
        const CntJob& J = pa.cb.j[r];
        int e = (bx - J.bstart) * 256 + threadIdx.x;
        if (e < J.E) {
            int rk = atomicAdd(&J.deg[J.dst[e]], 1);
            J.rank[e] = (ushort_t)rk;
            J.pw[e] = ((uint_t)f2bf(J.w[e]) << 16) | (uint_t)J.src[e];
        }
        return;
    }
    bx -= pa.bsC;
    if (bx < pa.bsT) {
        int r = 0;
#pragma unroll
        for (int i = 1; i < 6; ++i) r = (bx >= pa.tb.j[i].bstart) ? i : r;
        const TrJob& J = pa.tb.j[r];
        int local = bx - J.bstart;
        int b = local / J.nxy, rem = local % J.nxy;
        int n0 = (rem % J.nx) * 32, k0 = (rem / J.nx) * 32;
        const float* s = J.src + (size_t)b * J.K * J.N;
        ushort_t* d = J.dst + (size_t)b * J.K * J.N;
        int x = threadIdx.x & 31, y = threadIdx.x >> 5;
        for (int i = y; i < 32; i += 8) {
            int k = k0 + i, n = n0 + x;
            t[i][x] = (k < J.K && n < J.N) ? f2bf(s[(size_t)k * J.N + n]) : (ushort_t)0;
        }
        __syncthreads();
        for (int i = y; i < 32; i += 8) {
            int n = n0 + i, k = k0 + x;
            if (n < J.N && k < J.K) d[(size_t)n * J.K + k] = t[x][i];
        }
        return;
    }
    bx -= pa.bsT;
    int i = bx * 256 + threadIdx.x;
    if (i < pa.nEmb) {
        int r = i >> 8, c = i & 255;
        int j = pa.pidx[r];
        j = (uint_t)j < (uint_t)NPP ? j : 0;
        pa.hp[i] = f2bf(pa.emb[(size_t)j * 256 + c]);
    }
}

// shfl-based scan: 3 barriers per 1024-chunk.
__global__ __launch_bounds__(1024) void sc_csr_scan6(const int* __restrict__ deg_base,
                                                     int* __restrict__ offs_base) {
    const int ndst[6] = {NCC, NGG, NPP, NGG, NGG, NPP};
    const int dstart[6] = {0, NCC, NCC + NGG, NCC + NGG + NPP, NCC + 2 * NGG + NPP,
                           NCC + 3 * NGG + NPP};
    const int ostart[6] = {0, NCC + 1, NCC + NGG + 2, NCC + NGG + NPP + 3,
                           NCC + 2 * NGG + NPP + 4, NCC + 3 * NGG + NPP + 5};
    int r = blockIdx.x;
    const int* deg = deg_base + dstart[r];
    int* offs = offs_base + ostart[r];
    int n = ndst[r];
    __shared__ int wsum[16];
    __shared__ int carry;
    int tid = threadIdx.x, wave = tid >> 6, lane = tid & 63;
    if (tid == 0) carry = 0;
    __syncthreads();
    for (int base = 0; base < n; base += 1024) {
        int i = base + tid;
        int v = (i < n) ? deg[i] : 0;
        int x = v;
#pragma unroll
        for (int o = 1; o < 64; o <<= 1) {
            int tv = __shfl_up(x, o, 64);
            if (lane >= o) x += tv;
        }
        if (lane == 63) wsum[wave] = x;
        __syncthreads();
        if (tid == 0) {
            int acc = 0;
#pragma unroll
            for (int k = 0; k < 16; ++k) {
                int tv = wsum[k];
                wsum[k] = acc;
                acc += tv;
            }
        }
        __syncthreads();
        int incl = x + wsum[wave];
        int cr = carry;
        if (i < n) offs[i] = cr + incl - v;
        __syncthreads();
        if (tid == 1023) carry = cr + incl;
        __syncthreads();
    }
    if (tid == 0) offs[n] = carry;
}

// ================= GEMM body (128x64 tile) ==========
__device__ __forceinline__ void gemm_body(const GemmBatch& gbat, int mbx, int n0, ushort_t* As,
                                          ushort_t* Bs) {
    int r = 0;
#pragma unroll
    for (int i = 1; i < 7; ++i) r = (mbx >= gbat.j[i].mstart) ? i : r;
    const void* JA1 = gbat.j[r].A1;
    const int lda1 = gbat.j[r].lda1, K1j = gbat.j[r].K1, af1 = gbat.j[r].af1;
    const ushort_t* JBt1 = gbat.j[r].Bt1;
    const ushort_t* JA2 = gbat.j[r].A2;
    const int K2j = gbat.j[r].K2;
    const ushort_t* JBt2 = gbat.j[r].Bt2;
    const float* bias = gbat.j[r].bias;
    ushort_t* C = gbat.j[r].C;
    const int ldc = gbat.j[r].ldc, M = gbat.j[r].M;
    const int tid = threadIdx.x;
    const int wave = tid >> 6, lane = tid & 63;
    const int lr = lane & 15, lq = lane >> 4;
    const int m0 = (mbx - gbat.j[r].mstart) * 128;
    f32x4 acc[2][4] = {};
    for (int pass = 0; pass < 2; ++pass) {
        const void* A = pass ? (const void*)JA2 : JA1;
        const ushort_t* Bt = pass ? JBt2 : JBt1;
        const int K = pass ? K2j : K1j;
        const int lda = pass ? 256 : lda1;
        const int af = pass ? 0 : af1;
        if (K == 0 || A == nullptr) continue;
        for (int k0 = 0; k0 < K; k0 += 64) {
            __syncthreads();
#pragma unroll
            for (int i = 0; i < 4; ++i) {
                int g = tid + i * 256;
                int rr = g >> 3, c = (g & 7) * 8;
                ushortx8 v = {0, 0, 0, 0, 0, 0, 0, 0};
                int gm = m0 + rr;
                if (gm < M) {
                    if (af) {
                        const float* Af = (const float*)A;
                        float4 f0 = *(const float4*)(Af + (size_t)gm * lda + k0 + c);
                        float4 f1 = *(const float4*)(Af + (size_t)gm * lda + k0 + c + 4);
                        v[0] = f2bf(f0.x);
                        v[1] = f2bf(f0.y);
                        v[2] = f2bf(f0.z);
                        v[3] = f2bf(f0.w);
                        v[4] = f2bf(f1.x);
                        v[5] = f2bf(f1.y);
                        v[6] = f2bf(f1.z);
                        v[7] = f2bf(f1.w);
                    } else {
                        v = *(const ushortx8*)((const ushort_t*)A + (size_t)gm * lda + k0 + c);
                    }
                }
                *(ushortx8*)(&As[rr * LDS_STR + c]) = v;
            }
#pragma unroll
            for (int i = 0; i < 2; ++i) {
                int g = tid + i * 256;
                int rr = g >> 3, c = (g & 7) * 8;
                int gn = n0 + rr;
                ushortx8 v = *(const ushortx8*)(Bt + (size_t)gn * K + k0 + c);
                *(ushortx8*)(&Bs[rr * LDS_STR + c]) = v;
            }
            __syncthreads();
#pragma unroll
            for (int kk = 0; kk < 64; kk += 32) {
                bf16x8 a0 = __builtin_bit_cast(
                    bf16x8, *(const ushortx8*)(&As[(wave * 32 + lr) * LDS_STR + kk + lq * 8]));
                bf16x8 a1 = __builtin_bit_cast(
                    bf16x8,
                    *(const ushortx8*)(&As[(wave * 32 + 16 + lr) * LDS_STR + kk + lq * 8]));
                bf16x8 b0 = __builtin_bit_cast(
                    bf16x8, *(const ushortx8*)(&Bs[(lr)*LDS_STR + kk + lq * 8]));
                bf16x8 b1 = __builtin_bit_cast(
                    bf16x8, *(const ushortx8*)(&Bs[(16 + lr) * LDS_STR + kk + lq * 8]));
                bf16x8 b2 = __builtin_bit_cast(
                    bf16x8, *(const ushortx8*)(&Bs[(32 + lr) * LDS_STR + kk + lq * 8]));
                bf16x8 b3 = __builtin_bit_cast(
                    bf16x8, *(const ushortx8*)(&Bs[(48 + lr) * LDS_STR + kk + lq * 8]));
                acc[0][0] = __builtin_amdgcn_mfma_f32_16x16x32_bf16(a0, b0, acc[0][0], 0, 0, 0);
                acc[0][1] = __builtin_amdgcn_mfma_f32_16x16x32_bf16(a0, b1, acc[0][1], 0, 0, 0);
                acc[0][2] = __builtin_amdgcn_mfma_f32_16x16x32_bf16(a0, b2, acc[0][2], 0, 0, 0);
                acc[0][3] = __builtin_amdgcn_mfma_f32_16x16x32_bf16(a0, b3, acc[0][3], 0, 0, 0);
                acc[1][0] = __builtin_amdgcn_mfma_f32_16x16x32_bf16(a1, b0, acc[1][0], 0, 0, 0);
                acc[1][1] = __builtin_amdgcn_mfma_f32_16x16x32_bf16(a1, b1, acc[1][1], 0, 0, 0);
                acc[1][2] = __builtin_amdgcn_mfma_f32_16x16x32_bf16(a1, b2, acc[1][2], 0, 0, 0);
                acc[1][3] = __builtin_amdgcn_mfma_f32_16x16x32_bf16(a1, b3, acc[1][3], 0, 0, 0);
            }
        }
    }
#pragma unroll
    for (int mt = 0; mt < 2; ++mt)
#pragma unroll
        for (int nt = 0; nt < 4; ++nt) {
            int col = n0 + nt * 16 + lr;
            float bb = bias[col];
#pragma unroll
            for (int v = 0; v < 4; ++v) {
                int row = m0 + wave * 32 + mt * 16 + lq * 4 + v;
                if (row >= M) continue;
                C[(size_t)row * ldc + col] = f2bf(scrub(acc[mt][nt][v] + bb));
            }
        }
}

// ---------------- batched GEMMs (2D grid, layer use) ----------------
__global__ __launch_bounds__(256) void sc_gemm_batch(GemmBatch gbat) {
    __shared__ __align__(16) ushort_t As[128 * LDS_STR];
    __shared__ __align__(16) ushort_t Bs[64 * LDS_STR];
    gemm_body(gbat, blockIdx.x, blockIdx.y * 64, As, Bs);
}

// ---------------- merged: CSR fill (BW-bound) + emb GEMMs (MFMA-bound) ----------------
struct FillGemmArgs {
    GemmBatch gb;
    int gemmBlocks;  // ms*4 flattened (mb = bx>>2, ntile = bx&3)
    FillBatch fb;
};
__global__ __launch_bounds__(256) void sc_fill_gemm(FillGemmArgs fg) {
    __shared__ __align__(16) ushort_t As[128 * LDS_STR];
    __shared__ __align__(16) ushort_t Bs[64 * LDS_STR];
    int bx = blockIdx.x;
    if (bx >= fg.gemmBlocks) {
        bx -= fg.gemmBlocks;
        int r = 0;
#pragma unroll
        for (int i = 1; i < 6; ++i) r = (bx >= fg.fb.j[i].bstart) ? i : r;
        const FillJob& J = fg.fb.j[r];
        int e = (bx - J.bstart) * 256 + threadIdx.x;
        if (e < J.E) {
            int d = J.dst[e];
            J.ep[J.offs[d] + (int)J.rank[e]] = J.pw[e];
        }
        return;
    }
    gemm_body(fg.gb, bx >> 2, (bx & 3) * 64, As, Bs);
}

// ---------------- SAGE neighbor mean: all 6 relations, unroll-16 ILP ----------------
// Standalone (NO LDS, 16 VGPR): latency-bound => needs max occupancy (r12 lesson).
struct GatherJob {
    const ushort_t* hsrc;
    int src_ld, src_n;
    const int* offs;
    const uint_t* ep;
    ushort_t* out;
    int row_start;
};
struct GatherBatch {
    GatherJob j[6];
};
__global__ __launch_bounds__(256) void sc_gather_all(GatherBatch gb, int total_rows) {
    int grow = blockIdx.x * 4 + (threadIdx.x >> 6);
    if (grow >= total_rows) return;
    int r = 0;
#pragma unroll
    for (int i = 1; i < 6; ++i) r = (grow >= gb.j[i].row_start) ? i : r;
    r = __builtin_amdgcn_readfirstlane(r);  // wave-uniform: scalar descriptor loads
    const ushort_t* hsrc = gb.j[r].hsrc;
    const int src_ld = gb.j[r].src_ld, src_n = gb.j[r].src_n;
    const int* offs = gb.j[r].offs;
    const uint_t* ep = gb.j[r].ep;
    ushort_t* out = gb.j[r].out;
    int row = grow - gb.j[r].row_start;
    int lane = threadIdx.x & 63, c = lane * 4;
    int s0 = offs[row], s1 = offs[row + 1];
    float a0 = 0.f, a1 = 0.f, a2 = 0.f, a3 = 0.f;
    for (int base = s0; base < s1; base += 64) {
        int e = base + lane;
        uint_t myp = (e < s1) ? ep[e] : 0u;  // pad lanes: src=0, w=bf16(0)=+0
        int cnt = s1 - base;
        cnt = cnt < 64 ? cnt : 64;
        int cnt16 = (cnt + 15) & ~15;  // padded groups add w=0 terms
        for (int jj = 0; jj < cnt16; jj += 16) {
#pragma unroll
            for (int u = 0; u < 16; ++u) {  // 16 independent gather loads in flight
                uint_t pw = (uint_t)__shfl((int)myp, jj + u, 64);
                int s = (int)(pw & 0xFFFFu);
                s = (uint_t)s < (uint_t)src_n ? s : 0;  // clamp: defects->wrong, not wild
                float w = bf2f((ushort_t)(pw >> 16));
                ushortx4 v = *(const ushortx4*)(hsrc + (size_t)s * src_ld + c);
                a0 += w * bf2f(v[0]);
                a1 += w * bf2f(v[1]);
                a2 += w * bf2f(v[2]);
                a3 += w * bf2f(v[3]);
            }
        }
    }
    float inv = 1.f / fmaxf((float)(s1 - s0), 1.f);
    ushort_t* o = out + (size_t)row * 256 + c;
    o[0] = f2bf(scrub(a0 * inv));
    o[1] = f2bf(scrub(a1 * inv));
    o[2] = f2bf(scrub(a2 * inv));
    o[3] = f2bf(scrub(a3 * inv));
}

// ---------------- standalone MFMA bf16 GEMM (final proj, f32 out) ----------------
__global__ __launch_bounds__(256) void sc_gemm(const ushort_t* __restrict__ A1, int lda1,
                                               const ushort_t* __restrict__ Bt1, int K1,
                                               const float* __restrict__ bias,
                                               float* __restrict__ Cf, int ldc, int M, int N) {
    __shared__ __align__(16) ushort_t As[128 * LDS_STR];
    __shared__ __align__(16) ushort_t Bs[64 * LDS_STR];
    const int tid = threadIdx.x;
    const int wave = tid >> 6, lane = tid & 63;
    const int lr = lane & 15, lq = lane >> 4;
    const int m0 = blockIdx.x * 128, n0 = blockIdx.y * 64;
    f32x4 acc[2][4] = {};
    for (int k0 = 0; k0 < K1; k0 += 64) {
        __syncthreads();
#pragma unroll
        for (int i = 0; i < 4; ++i) {
            int g = tid + i * 256;
            int r = g >> 3, c = (g & 7) * 8;
            ushortx8 v = {0, 0, 0, 0, 0, 0, 0, 0};
            int gm = m0 + r;
            if (gm < M) v = *(const ushortx8*)(A1 + (size_t)gm * lda1 + k0 + c);
            *(ushortx8*)(&As[r * LDS_STR + c]) = v;
        }
#pragma unroll
        for (int i = 0; i < 2; ++i) {
            int g = tid + i * 256;
            int r = g >> 3, c = (g & 7) * 8;
            ushortx8 v = {0, 0, 0, 0, 0, 0, 0, 0};
            int gn = n0 + r;
            if (gn < N) v = *(const ushortx8*)(Bt1 + (size_t)gn * K1 + k0 + c);
            *(ushortx8*)(&Bs[r * LDS_STR + c]) = v;
        }
        __syncthreads();
#pragma unroll
        for (int kk = 0; kk < 64; kk += 32) {
            bf16x8 a0 = __builtin_bit_cast(
                bf16x8, *(const ushortx8*)(&As[(wave * 32 + lr) * LDS_STR + kk + lq * 8]));
            bf16x8 a1 = __builtin_bit_cast(
                bf16x8, *(const ushortx8*)(&As[(wave * 32 + 16 + lr) * LDS_STR + kk + lq * 8]));
            bf16x8 b0 =
                __builtin_bit_cast(bf16x8, *(const ushortx8*)(&Bs[(lr)*LDS_STR + kk + lq * 8]));
            bf16x8 b1 = __builtin_bit_cast(
                bf16x8, *(const ushortx8*)(&Bs[(16 + lr) * LDS_STR + kk + lq * 8]));
            bf16x8 b2 = __builtin_bit_cast(
                bf16x8, *(const ushortx8*)(&Bs[(32 + lr) * LDS_STR + kk + lq * 8]));
            bf16x8 b3 = __builtin_bit_cast(
                bf16x8, *(const ushortx8*)(&Bs[(48 + lr) * LDS_STR + kk + lq * 8]));
            acc[0][0] = __builtin_amdgcn_mfma_f32_16x16x32_bf16(a0, b0, acc[0][0], 0, 0, 0);
            acc[0][1] = __builtin_amdgcn_mfma_f32_16x16x32_bf16(a0, b1, acc[0][1], 0, 0, 0);
            acc[0][2] = __builtin_amdgcn_mfma_f32_16x16x32_bf16(a0, b2, acc[0][2], 0, 0, 0);
            acc[0][3] = __builtin_amdgcn_mfma_f32_16x16x32_bf16(a0, b3, acc[0][3], 0, 0, 0);
            acc[1][0] = __builtin_amdgcn_mfma_f32_16x16x32_bf16(a1, b0, acc[1][0], 0, 0, 0);
            acc[1][1] = __builtin_amdgcn_mfma_f32_16x16x32_bf16(a1, b1, acc[1][1], 0, 0, 0);
            acc[1][2] = __builtin_amdgcn_mfma_f32_16x16x32_bf16(a1, b2, acc[1][2], 0, 0, 0);
            acc[1][3] = __builtin_amdgcn_mfma_f32_16x16x32_bf16(a1, b3, acc[1][3], 0, 0, 0);
        }
    }
#pragma unroll
    for (int mt = 0; mt < 2; ++mt)
#pragma unroll
        for (int nt = 0; nt < 4; ++nt) {
            int col = n0 + nt * 16 + lr;
            if (col >= N) continue;
            float bb = bias ? bias[col] : 0.f;
#pragma unroll
            for (int v = 0; v < 4; ++v) {
                int row = m0 + wave * 32 + mt * 16 + lq * 4 + v;
                if (row >= M) continue;
                Cf[(size_t)row * ldc + col] = scrub(acc[mt][nt][v] + bb);
            }
        }
}

// ---------------- fused selu+LN chains, 3 node types in one dispatch ----------------
struct LnJob {
    const ushort_t *sA, *sB, *sC;
    const float *g1, *b1, *g2, *b2;
    ushort_t* out;
    int out_ld;
    int row_start;
};
struct LnBatch {
    LnJob j[3];
};
__global__ __launch_bounds__(256) void sc_fuse_ln_all(LnBatch lb, int total_rows) {
    int grow = blockIdx.x * 4 + (threadIdx.x >> 6);
    if (grow >= total_rows) return;
    int r = 0;
#pragma unroll
    for (int i = 1; i < 3; ++i) r = (grow >= lb.j[i].row_start) ? i : r;
    r = __builtin_amdgcn_readfirstlane(r);
    const ushort_t* srcs[3] = {lb.j[r].sA, lb.j[r].sB, lb.j[r].sC};
    const float* g1 = lb.j[r].g1;
    const float* b1 = lb.j[r].b1;
    const float* g2 = lb.j[r].g2;
    const float* b2 = lb.j[r].b2;
    ushort_t* out = lb.j[r].out;
    int out_ld = lb.j[r].out_ld;
    int row = grow - lb.j[r].row_start;
    int lane = threadIdx.x & 63, c = lane * 4;
    float t[4] = {0.f, 0.f, 0.f, 0.f};
#pragma unroll
    for (int si = 0; si < 3; ++si) {
        const ushort_t* s = srcs[si];
        if (!s) continue;
        ushortx4 v = *(const ushortx4*)(s + (size_t)row * 256 + c);
        float x0 = selu_f(scrub(bf2f(v[0]))), x1 = selu_f(scrub(bf2f(v[1])));
        float x2 = selu_f(scrub(bf2f(v[2]))), x3 = selu_f(scrub(bf2f(v[3])));
        float mu = wsum64(x0 + x1 + x2 + x3) * (1.f / 256.f);
        float d0 = x0 - mu, d1 = x1 - mu, d2 = x2 - mu, d3 = x3 - mu;
        float var = wsum64(d0 * d0 + d1 * d1 + d2 * d2 + d3 * d3) * (1.f / 256.f);
        float rr = rsqrtf(var + 1e-5f);
        t[0] += d0 * rr * g1[c + 0] + b1[c + 0];
        t[1] += d1 * rr * g1[c + 1] + b1[c + 1];
        t[2] += d2 * rr * g1[c + 2] + b1[c + 2];
        t[3] += d3 * rr * g1[c + 3] + b1[c + 3];
    }
    float x0 = selu_f(scrub(t[0])), x1 = selu_f(scrub(t[1]));
    float x2 = selu_f(scrub(t[2])), x3 = selu_f(scrub(t[3]));
    float mu = wsum64(x0 + x1 + x2 + x3) * (1.f / 256.f);
    float d0 = x0 - mu, d1 = x1 - mu, d2 = x2 - mu, d3 = x3 - mu;
    float var = wsum64(d0 * d0 + d1 * d1 + d2 * d2 + d3 * d3) * (1.f / 256.f);
    float rr = rsqrtf(var + 1e-5f);
    ushort_t* o = out + (size_t)row * out_ld + c;
    o[0] = f2bf(scrub(d0 * rr * g2[c + 0] + b2[c + 0]));
    o[1] = f2bf(scrub(d1 * rr * g2[c + 1] + b2[c + 1]));
    o[2] = f2bf(scrub(d2 * rr * g2[c + 2] + b2[c + 2]));
    o[3] = f2bf(scrub(d3 * rr * g2[c + 3] + b2[c + 3]));
}

static inline int cdivi(int a, int b) { return (a + b - 1) / b; }

extern "C" void kernel_launch(void* const* d_in, const int* in_sizes, int n_in, void* d_out,
                              int out_size, void* d_ws, size_t ws_size, hipStream_t stream) {
    const float* cell_feat = (const float*)d_in[0];
    const float* gene_feat = (const float*)d_in[1];
    const int* pro_idx = (const int*)d_in[2];
    const int* edge_src[6] = {(const int*)d_in[3],  (const int*)d_in[6],  (const int*)d_in[9],
                              (const int*)d_in[12], (const int*)d_in[15], (const int*)d_in[18]};
    const int* edge_dst[6] = {(const int*)d_in[4],  (const int*)d_in[7],  (const int*)d_in[10],
                              (const int*)d_in[13], (const int*)d_in[16], (const int*)d_in[19]};
    const float* edge_w[6] = {(const float*)d_in[5],  (const float*)d_in[8],
                              (const float*)d_in[11], (const float*)d_in[14],
                              (const float*)d_in[17], (const float*)d_in[20]};
    const float* W_emb_cell = (const float*)d_in[21];
    const float* b_emb_cell = (const float*)d_in[22];
    const float* W_emb_gene = (const float*)d_in[23];
    const float* b_emb_gene = (const float*)d_in[24];
    const float* emb_pro = (const float*)d_in[25];
    const float* W_mlpcell = (const float*)d_in[26];
    const float* b_mlpcell = (const float*)d_in[27];
    const float* W_sage_self = (const float*)d_in[28];
    const float* W_sage_neigh = (const float*)d_in[29];
    const float* b_sage = (const float*)d_in[30];
    const float* ln1_g = (const float*)d_in[31];
    const float* ln1_b = (const float*)d_in[32];
    const float* ln2_g = (const float*)d_in[33];
    const float* ln2_b = (const float*)d_in[34];
    const float* W_last = (const float*)d_in[35];
    const float* b_last = (const float*)d_in[36];

    const int E_obs = in_sizes[3], E_sym = in_sizes[9], E_coexp = in_sizes[15],
              E_ppi = in_sizes[18];
    const int Er[6] = {E_obs, E_obs, E_sym, E_sym, E_coexp, E_ppi};
    const int Nd[6] = {NCC, NGG, NPP, NGG, NGG, NPP};

    // ---- workspace carve ----
    char* p = (char*)d_ws;
    auto carve = [&](size_t bytes) -> char* {
        char* r = p;
        p += ((bytes + 255) & ~(size_t)255);
        return r;
    };
    ushort_t* hist = (ushort_t*)carve((size_t)NCC * 768 * 2);
    ushort_t* hg = (ushort_t*)carve((size_t)NGG * 256 * 2);
    ushort_t* hp = (ushort_t*)carve((size_t)NPP * 256 * 2);
    ushort_t* n_obs = (ushort_t*)carve((size_t)NCC * 256 * 2);
    ushort_t* n_robs = (ushort_t*)carve((size_t)NGG * 256 * 2);
    ushort_t* n_sym = (ushort_t*)carve((size_t)NPP * 256 * 2);
    ushort_t* n_rsym = (ushort_t*)carve((size_t)NGG * 256 * 2);
    ushort_t* n_coexp = (ushort_t*)carve((size_t)NGG * 256 * 2);
    ushort_t* n_ppi = (ushort_t*)carve((size_t)NPP * 256 * 2);
    ushort_t* s_obs = (ushort_t*)carve((size_t)NCC * 256 * 2);
    ushort_t* s_robs = (ushort_t*)carve((size_t)NGG * 256 * 2);
    ushort_t* s_sym = (ushort_t*)carve((size_t)NPP * 256 * 2);
    ushort_t* s_rsym = (ushort_t*)carve((size_t)NGG * 256 * 2);
    ushort_t* s_coexp = (ushort_t*)carve((size_t)NGG * 256 * 2);
    ushort_t* s_ppi = (ushort_t*)carve((size_t)NPP * 256 * 2);
    ushort_t* s_mlp = (ushort_t*)carve((size_t)NCC * 256 * 2);
    ushort_t* Wt_emb_cell = (ushort_t*)carve((size_t)512 * 256 * 2);
    ushort_t* Wt_emb_gene = (ushort_t*)carve((size_t)512 * 256 * 2);
    ushort_t* Wt_mlp = (ushort_t*)carve((size_t)2 * 256 * 256 * 2);
    ushort_t* Wt_self = (ushort_t*)carve((size_t)12 * 256 * 256 * 2);
    ushort_t* Wt_neigh = (ushort_t*)carve((size_t)12 * 256 * 256 * 2);
    ushort_t* Wt_last = (ushort_t*)carve((size_t)140 * 768 * 2);
    const int NDTOT = NCC + 3 * NGG + 2 * NPP;  // 20760
    int* deg_all = (int*)carve((size_t)NDTOT * 4);
    int* offs_all = (int*)carve((size_t)(NDTOT + 6) * 4);
    const int ETOT = 2 * E_obs + 2 * E_sym + E_coexp + E_ppi;
    uint_t* pw_all = (uint_t*)carve((size_t)ETOT * 4);        // packed, edge order
    ushort_t* rank_all = (ushort_t*)carve((size_t)ETOT * 2);  // rank within dst group
    uint_t* ep_all = (uint_t*)carve((size_t)ETOT * 4);        // packed, CSR order
    (void)ws_size;
    (void)n_in;
    (void)out_size;

    const int dS[6] = {0, NCC, NCC + NGG, NCC + NGG + NPP, NCC + 2 * NGG + NPP,
                       NCC + 3 * NGG + NPP};
    const int oS[6] = {0, NCC + 1, NCC + NGG + 2, NCC + NGG + NPP + 3, NCC + 2 * NGG + NPP + 4,
                       NCC + 3 * NGG + NPP + 5};
    int eS[6];
    eS[0] = 0;
    eS[1] = eS[0] + E_obs;
    eS[2] = eS[1] + E_obs;
    eS[3] = eS[2] + E_sym;
    eS[4] = eS[3] + E_sym;
    eS[5] = eS[4] + E_coexp;

    // ---- zero deg, then merged prep (count+rank+pack | transposes | emb gather) ----
    sc_zero1<<<cdivi(NDTOT, 256), 256, 0, stream>>>(deg_all, NDTOT);
    {
        PrepArgs pa;
        int bs = 0;
        for (int r = 0; r < 6; ++r) {
            pa.cb.j[r] = {edge_dst[r], edge_src[r], edge_w[r], pw_all + eS[r], rank_all + eS[r],
                          Er[r], deg_all + dS[r], bs};
            bs += cdivi(Er[r], 256);
        }
        pa.bsC = bs;
        int bt = 0;
        auto add = [&](int idx, const float* s, ushort_t* d, int B, int K, int N) {
            int nx = cdivi(N, 32), ny = cdivi(K, 32);
            pa.tb.j[idx] = {s, d, K, N, nx, nx * ny, bt};
            bt += B * nx * ny;
        };
        add(0, W_emb_cell, Wt_emb_cell, 1, 512, 256);
        add(1, W_emb_gene, Wt_emb_gene, 1, 512, 256);
        add(2, W_mlpcell, Wt_mlp, 2, 256, 256);
        add(3, W_sage_self, Wt_self, 12, 256, 256);
        add(4, W_sage_neigh, Wt_neigh, 12, 256, 256);
        add(5, W_last, Wt_last, 1, 768, 140);
        pa.bsT = bt;
        pa.emb = emb_pro;
        pa.pidx = pro_idx;
        pa.hp = hp;
        pa.nEmb = NPP * 256;
        int bsE = cdivi(NPP * 256, 256);
        sc_prep<<<pa.bsC + pa.bsT + bsE, 256, 0, stream>>>(pa);
    }
    sc_csr_scan6<<<6, 1024, 0, stream>>>(deg_all, offs_all);
    // ---- merged: CSR fill + both emb GEMMs (independent; BW + MFMA overlap) ----
    {
        FillGemmArgs fg;
        for (int i = 0; i < 7; ++i) fg.gb.j[i].mstart = 0x7FFFFFFF;
        fg.gb.j[0] = {cell_feat, 512, 512, 1, Wt_emb_cell, nullptr, 0, nullptr, b_emb_cell, hist,
                      768, NCC, 0};
        fg.gb.j[1] = {gene_feat, 512, 512, 1, Wt_emb_gene, nullptr, 0, nullptr, b_emb_gene, hg,
                      256, NGG, 64};
        fg.gemmBlocks = 96 * 4;
        int bs = 0;
        for (int r = 0; r < 6; ++r) {
            fg.fb.j[r] = {edge_dst[r], pw_all + eS[r], rank_all + eS[r], Er[r], offs_all + oS[r],
                          ep_all + eS[r], bs};
            bs += cdivi(Er[r], 256);
        }
        sc_fill_gemm<<<fg.gemmBlocks + bs, 256, 0, stream>>>(fg);
    }

    // ---- layers ----
    for (int l = 0; l < 2; ++l) {
        const ushort_t* hc_l = hist + l * 256;  // row stride 768
        // all 6 neighbor-mean gathers in one dispatch
        {
            GatherBatch gb;
            const ushort_t* hs[6] = {hg, hc_l, hg, hp, hg, hp};
            const int lds[6] = {256, 768, 256, 256, 256, 256};
            const int sn[6] = {NGG, NCC, NGG, NPP, NGG, NPP};
            ushort_t* outs[6] = {n_obs, n_robs, n_sym, n_rsym, n_coexp, n_ppi};
            int rs = 0;
            for (int r = 0; r < 6; ++r) {
                gb.j[r] = {hs[r], lds[r], sn[r], offs_all + oS[r], ep_all + eS[r], outs[r], rs};
                rs += Nd[r];
            }
            sc_gather_all<<<cdivi(rs, 4), 256, 0, stream>>>(gb, rs);
        }
        // mlp + 6 relation GEMMs in one dispatch
        {
            const size_t WSZ = 65536;
            GemmBatch gbat;
            gbat.j[0] = {hc_l, 768, 256, 0, Wt_mlp + (size_t)l * WSZ, nullptr, 0, nullptr,
                         b_mlpcell + l * 256, s_mlp, 256, NCC, 0};
            const ushort_t* dstf[6] = {hc_l, hg, hp, hg, hg, hp};
            const int dld[6] = {768, 256, 256, 256, 256, 256};
            const ushort_t* nb[6] = {n_obs, n_robs, n_sym, n_rsym, n_coexp, n_ppi};
            ushort_t* so[6] = {s_obs, s_robs, s_sym, s_rsym, s_coexp, s_ppi};
            int ms = cdivi(NCC, 128);
            for (int r = 0; r < 6; ++r) {
                gbat.j[r + 1] = {dstf[r],
                                 dld[r],
                                 256,
                                 0,
                                 Wt_self + (size_t)(l * 6 + r) * WSZ,
                                 nb[r],
                                 256,
                                 Wt_neigh + (size_t)(l * 6 + r) * WSZ,
                                 b_sage + (l * 6 + r) * 256,
                                 so[r],
                                 256,
                                 Nd[r],
                                 ms};
                ms += cdivi(Nd[r], 128);
            }
            sc_gemm_batch<<<dim3(ms, 4), 256, 0, stream>>>(gbat);
        }
        // 3 fused selu+LN chains in one dispatch
        {
            LnBatch lb;
            lb.j[0] = {s_robs, s_rsym, s_coexp, ln1_g + (l * 3 + 0) * 256,
                       ln1_b + (l * 3 + 0) * 256, ln2_g + (l * 3 + 0) * 256,
                       ln2_b + (l * 3 + 0) * 256, hg, 256, 0};
            lb.j[1] = {s_sym, s_ppi, nullptr, ln1_g + (l * 3 + 1) * 256,
                       ln1_b + (l * 3 + 1) * 256, ln2_g + (l * 3 + 1) * 256,
                       ln2_b + (l * 3 + 1) * 256, hp, 256, NGG};
            lb.j[2] = {s_obs, s_mlp, nullptr, ln1_g + (l * 3 + 2) * 256,
                       ln1_b + (l * 3 + 2) * 256, ln2_g + (l * 3 + 2) * 256,
                       ln2_b + (l * 3 + 2) * 256, hist + (l + 1) * 256, 768, NGG + NPP};
            int rs = NGG + NPP + NCC;
            sc_fuse_ln_all<<<cdivi(rs, 4), 256, 0, stream>>>(lb, rs);
        }
    }

    // ---- final projection: out(f32) = hist[8192,768] @ W_last + b_last ----
    sc_gemm<<<dim3(64, 3), 256, 0, stream>>>(hist, 768, Wt_last, 768, b_last, (float*)d_out, 140,
                                             NCC, 140);
}